// Round 11
// baseline (108.667 us; speedup 1.0000x reference)
//
#include <hip/hip_runtime.h>

// DigitCaps on MI355X, fp32 I/O, R11.
// R2: fp32 atomicAdd = CAS loop -> native int LDS atomics only.
// R3: seg sums winner-biased -> int64/exact finals.
// R5/R6/R8: ANY __launch_bounds__ VGPR cap -> catastrophic scratch spill
//   (WRITE_SIZE is the spill detector). Uncapped ~200-reg design is the only
//   non-spilling config; 2 waves/SIMD is the price.
// R9/R10: 99-101us total. Profile: harness fill of 256MiB d_ws (43.5us @78%
//   HBM peak) + d_in restore (~8us) + dispatch gaps = ~52-55us FIXED floor.
//   s-bank-conflict fix was neutral -> LDS atomics overlap the busier VALU.
// R11: (a) 576 fat blocks (128 b x 16 iters): halves startup (W/dc reg fill,
//   LDS zero) + halves part_seg flush. (b) layout m=t&3 -> sum q over the m
//   quad with 2 VALU DPP butterflies (quad_perm, no LDS pipe); only m==0
//   lanes issue s atomics (bank work /4).
//
// Sizes: B=128, J=4608, INPUT_D=8, D=8, M=4 -> N=18432 votes, C=10.
// Output = concat(output[128,10], digit_caps_new[10,8]).
// Math: output[b,c] = <(1/N) sum_n u[b,n], dc_new[c]> -> only s[b,:] needed.
//
// ws layout (4B units):
//   [0]                done counter
//   [64, 55360)        part_seg int [576][96] (col c*9+d; d==8 -> count)
//   [55360, 645184)    part_s int [576][1024] (col = b*8+d, scale 2^15)
//   [645184, 646208)   s_final float [1024]
//   ll units [323104, 323488)  seg_part long long [4][96]

#define J_POS 4608
#define SEGSTRIDE 97        // 97%32=1 -> seg replica r occupies bank shift r
#define NSEG 32
#define SSTRIDE 1025        // 1025%32=1 -> bank=(8*brow+d+jj)%32: 16 active lanes, 16 banks
#define NSREP 8
#define NVOTES 18432.0f
#define DENOM  2359296.0f   // B*N
#define SEG_SCALE 32768.0f  // 2^15
#define INV_SEG_SCALE 3.0517578125e-5f
#define OFF_PART_SEG 64
#define OFF_PART_S   55360
#define OFF_S_FINAL  645184
#define OFF_SEG_PART_LL 323104

__global__ __launch_bounds__(256) void votes_kernel(
    const float* __restrict__ x,   // [B, J, 8]
    const float* __restrict__ w,   // [J, 8, 32]
    const float* __restrict__ dc,  // [10, 8]
    int* __restrict__ part_seg,
    int* __restrict__ part_s,
    int* __restrict__ done)
{
    __shared__ int seg_lds[NSEG * SEGSTRIDE];   // 12.4 KB
    __shared__ int s_lds[NSREP * SSTRIDE];      // 32.8 KB

    const int t  = threadIdx.x;
    const int j0 = blockIdx.x * 8;

    if (blockIdx.x == 0 && t == 0) *done = 0;   // reduce launches after us (stream order)

    for (int i = t; i < NSEG * SEGSTRIDE; i += 256) seg_lds[i] = 0;
    for (int i = t; i < NSREP * SSTRIDE; i += 256) s_lds[i] = 0;

    const int m    = t & 3;            // vote column: quad lanes -> DPP-reducible
    const int jj   = (t >> 2) & 7;     // this thread's j
    const int brow = t >> 5;           // 0..7 : batch row within iter
    const int j = j0 + jj;

    // ---- W slice (8 i x 8 d for this (j,m)) -> 64 registers, loaded once
    float4 wra[8], wrb[8];
    {
        const float* wp = w + (size_t)j * 256 + m * 8;
        #pragma unroll
        for (int i = 0; i < 8; ++i) {
            wra[i] = *(const float4*)(wp + i * 32);
            wrb[i] = *(const float4*)(wp + i * 32 + 4);
        }
    }
    // ---- all of dc -> 80 registers (broadcast reads, L2-served)
    float4 dca[10], dcb[10];
    #pragma unroll
    for (int c = 0; c < 10; ++c) {
        dca[c] = *(const float4*)(dc + c * 8);
        dcb[c] = *(const float4*)(dc + c * 8 + 4);
    }

    int* const segp = &seg_lds[((t >> 1) & (NSEG - 1)) * SEGSTRIDE];
    int* const sp   = &s_lds[jj * SSTRIDE];   // active s-lanes (m==0): replica = jj

    __syncthreads();

    // ---- depth-2 software-pipelined x loads (~900cyc HBM latency)
    float4 nx0, nx1, mx0, mx1;
    {
        const float* xp = x + ((size_t)brow * J_POS + j) * 8;
        nx0 = *(const float4*)xp; nx1 = *(const float4*)(xp + 4);
        const float* xq = x + ((size_t)(8 + brow) * J_POS + j) * 8;
        mx0 = *(const float4*)xq; mx1 = *(const float4*)(xq + 4);
    }

    #pragma unroll 1
    for (int it = 0; it < 16; ++it) {
        const int bl = it * 8 + brow;       // b 0..127
        const float4 x0 = nx0, x1 = nx1;
        nx0 = mx0; nx1 = mx1;
        if (it < 14) {
            const float* xp = x + ((size_t)((it + 2) * 8 + brow) * J_POS + j) * 8;
            mx0 = *(const float4*)xp;
            mx1 = *(const float4*)(xp + 4);
        }
        const float xf[8] = {x0.x,x0.y,x0.z,x0.w,x1.x,x1.y,x1.z,x1.w};

        // ---- one vote: u[8], all operands in registers
        float u[8] = {0,0,0,0,0,0,0,0};
        #pragma unroll
        for (int i = 0; i < 8; ++i) {
            const float xi = xf[i];
            u[0] += xi * wra[i].x; u[1] += xi * wra[i].y;
            u[2] += xi * wra[i].z; u[3] += xi * wra[i].w;
            u[4] += xi * wrb[i].x; u[5] += xi * wrb[i].y;
            u[6] += xi * wrb[i].z; u[7] += xi * wrb[i].w;
        }

        // ---- argmax over 10 caps, dc in registers (strict > = first max, jnp)
        float best = -3.402823466e38f;
        int bc = 0;
        #pragma unroll
        for (int c = 0; c < 10; ++c) {
            const float sim = u[0]*dca[c].x + u[1]*dca[c].y + u[2]*dca[c].z + u[3]*dca[c].w
                            + u[4]*dcb[c].x + u[5]*dcb[c].y + u[6]*dcb[c].z + u[7]*dcb[c].w;
            if (sim > best) { best = sim; bc = c; }
        }

        // ---- quantize; seg atomics from all lanes (bc is data-dependent)
        int q[8];
        #pragma unroll
        for (int d = 0; d < 8; ++d) q[d] = __float2int_rn(u[d] * SEG_SCALE);

        const int o = bc * 9;
        #pragma unroll
        for (int d = 0; d < 8; ++d) atomicAdd(&segp[o + d], q[d]);
        atomicAdd(&segp[o + 8], 1);

        // ---- s: sum q over the m-quad with VALU-only DPP butterflies
        int sq[8];
        #pragma unroll
        for (int d = 0; d < 8; ++d) {
            int v = q[d];
            v += __builtin_amdgcn_update_dpp(0, v, 0xB1, 0xF, 0xF, true); // quad xor1
            v += __builtin_amdgcn_update_dpp(0, v, 0x4E, 0xF, 0xF, true); // quad xor2
            sq[d] = v;
        }
        if (m == 0) {       // 16 lanes/wave, banks (8*brow+d+jj)%32 all distinct
            const int sb = bl * 8;
            #pragma unroll
            for (int d = 0; d < 8; ++d) atomicAdd(&sp[sb + d], sq[d]);
        }
    }

    __syncthreads();

    // ---- flush partials: plain coalesced stores, zero global atomics
    if (t < 90) {
        int v = 0;
        #pragma unroll
        for (int r = 0; r < NSEG; ++r) v += seg_lds[r * SEGSTRIDE + t];
        part_seg[blockIdx.x * 96 + t] = v;
    }
    #pragma unroll
    for (int e = t; e < 1024; e += 256) {
        int v = 0;
        #pragma unroll
        for (int r = 0; r < NSREP; ++r) v += s_lds[r * SSTRIDE + e];
        part_s[(size_t)blockIdx.x * 1024 + e] = v;
    }
}

// 20 blocks: 0..15 s-columns, 16..19 seg-quarters; last-done block runs the final.
__global__ __launch_bounds__(256) void reduce_final_kernel(
    const int* __restrict__ part_seg,
    const int* __restrict__ part_s,
    float* __restrict__ s_final,
    long long* __restrict__ seg_part,
    int* __restrict__ done,
    const float* __restrict__ dc,
    float* __restrict__ out)       // [0,1280): output  [1280,1360): dc_new
{
    __shared__ long long red[64][5];
    __shared__ long long segred[2][96];
    __shared__ float dcn[80];
    __shared__ float sf[1024];
    __shared__ int lastflag;

    const int t = threadIdx.x;
    const int bid = blockIdx.x;

    if (bid < 16) {
        // ---- s column-reduce: 64 cols, 4 chunks of 144 rows (576 = 4*144)
        const int g0 = bid * 64;
        const int gl = t & 63, chunk = t >> 6;
        const int col = g0 + gl;
        long long acc = 0;
        #pragma unroll 8
        for (int i = chunk * 144; i < chunk * 144 + 144; ++i)
            acc += part_s[(size_t)i * 1024 + col];
        red[gl][chunk] = acc;
        __syncthreads();
        if (t < 64) {
            const long long v = red[t][0] + red[t][1] + red[t][2] + red[t][3];
            __hip_atomic_store(&s_final[g0 + t], (float)v * INV_SEG_SCALE,
                               __ATOMIC_RELAXED, __HIP_MEMORY_SCOPE_AGENT);
        }
    } else {
        // ---- seg quarter-reduce: 144 rows each, 96 cols, 2 row-chunks of 72
        const int p = bid - 16;
        if (t < 192) {
            const int o = t % 96, rc = t / 96;
            long long acc = 0;
            const int r0 = p * 144 + rc * 72;
            #pragma unroll 8
            for (int i = r0; i < r0 + 72; ++i)
                acc += part_seg[(size_t)i * 96 + o];
            segred[rc][o] = acc;
        }
        __syncthreads();
        if (t < 96)
            __hip_atomic_store(&seg_part[p * 96 + t], segred[0][t] + segred[1][t],
                               __ATOMIC_RELAXED, __HIP_MEMORY_SCOPE_AGENT);
    }

    // ---- completion protocol: release stores, count blocks, last one finalizes
    __threadfence();
    __syncthreads();
    if (t == 0) lastflag = (atomicAdd(done, 1) == 19) ? 1 : 0;
    __syncthreads();
    if (!lastflag) return;
    __threadfence();

    // ---- final (one block): dc_new + output GEMV; agent-scope loads of partials
    #pragma unroll
    for (int r = 0; r < 4; ++r) {
        const int i = r * 256 + t;
        const float v = __hip_atomic_load(&s_final[i], __ATOMIC_RELAXED,
                                          __HIP_MEMORY_SCOPE_AGENT);
        sf[i] = v * (1.0f / NVOTES);
    }
    if (t < 80) {
        const int c = t >> 3, d = t & 7;
        long long sv = 0, cv = 0;
        #pragma unroll
        for (int p = 0; p < 4; ++p) {
            sv += __hip_atomic_load(&seg_part[p * 96 + c * 9 + d], __ATOMIC_RELAXED,
                                    __HIP_MEMORY_SCOPE_AGENT);
            cv += __hip_atomic_load(&seg_part[p * 96 + c * 9 + 8], __ATOMIC_RELAXED,
                                    __HIP_MEMORY_SCOPE_AGENT);
        }
        const float d0 = dc[t];
        const float nd = d0 + ((float)sv * INV_SEG_SCALE - (float)cv * d0) * (1.0f / DENOM);
        dcn[t] = nd;
        out[1280 + t] = nd;
    }
    __syncthreads();

    #pragma unroll
    for (int r = 0; r < 5; ++r) {
        const int idx = r * 256 + t;        // 0..1279
        const int b = idx / 10, c = idx - b * 10;
        float acc = 0.f;
        #pragma unroll
        for (int d = 0; d < 8; ++d) acc += sf[b * 8 + d] * dcn[c * 8 + d];
        out[idx] = acc;
    }
}

extern "C" void kernel_launch(void* const* d_in, const int* in_sizes, int n_in,
                              void* d_out, int out_size, void* d_ws, size_t ws_size,
                              hipStream_t stream) {
    const float* x  = (const float*)d_in[0];
    const float* w  = (const float*)d_in[1];
    const float* dc = (const float*)d_in[2];
    float* out = (float*)d_out;
    int*       done      = (int*)d_ws;
    int*       part_seg  = (int*)d_ws + OFF_PART_SEG;
    int*       part_s    = (int*)d_ws + OFF_PART_S;
    float*     s_final   = (float*)d_ws + OFF_S_FINAL;
    long long* seg_part  = (long long*)d_ws + OFF_SEG_PART_LL;

    votes_kernel<<<576, 256, 0, stream>>>(x, w, dc, part_seg, part_s, done);
    reduce_final_kernel<<<20, 256, 0, stream>>>(part_seg, part_s, s_final,
                                                seg_part, done, dc, out);
}

// Round 12
// 98.966 us; speedup vs baseline: 1.0980x; 1.0980x over previous
//
#include <hip/hip_runtime.h>

// DigitCaps on MI355X, fp32 I/O, R12 == exact revert to R9 (best: 99.4us).
// Session evidence:
//   R2: fp32 atomicAdd = CAS loop -> native int LDS atomics only.
//   R3: seg sums winner-biased -> int64/exact finals.
//   R5/R7/R8: ANY __launch_bounds__ VGPR cap -> catastrophic scratch spill
//     (WRITE_SIZE is the spill detector). Uncapped ~216-reg design is the
//     only non-spilling config; 2 waves/SIMD is the price.
//   R9: register-resident W-slice + dc, one vote/thread/iter, replicated
//     fixed-point LDS atomics, plain-store flush -> 99.4us total.
//   R10 (s-bank fix + depth-2 prefetch): 101.4 neutral. R11 (fat blocks +
//     DPP quad reduce): 108.7 regression. LDS atomic bank work is NOT on
//     the critical path at 2 waves/SIMD; VALU+latency is.
//   Fixed floor: harness 256MiB d_ws re-poison fill = 43.5us @78% HBM peak
//     + d_in restore + dispatch gaps + reduce ~= 65-70us. votes ~20-25us
//     vs ~8us VALU-ideal; the gap is occupancy-bound latency.
//
// Sizes: B=128, J=4608, INPUT_D=8, D=8, M=4 -> N=18432 votes, C=10.
// Output = concat(output[128,10], digit_caps_new[10,8]).
// Math: output[b,c] = <(1/N) sum_n u[b,n], dc_new[c]> -> only s[b,:] needed.
//
// ws layout (4B units):
//   [0]                 done counter
//   [64, 110656)        part_seg int [1152][96] (col c*9+d; d==8 -> count)
//   [110656, 700480)    part_s int [1152][512] (col = local_b*8+d, scale 2^15)
//   [700480, 701504)    s_final float [1024]
//   ll units [350752, 351136)  seg_part long long [4][96]

#define J_POS 4608
#define SEGSTRIDE 97        // 97%32=1 -> replica r occupies bank r%32
#define NSEG 32
#define SSTRIDE 520
#define NSREP 8
#define NVOTES 18432.0f
#define DENOM  2359296.0f   // B*N
#define SEG_SCALE 32768.0f  // 2^15
#define INV_SEG_SCALE 3.0517578125e-5f
#define OFF_PART_SEG 64
#define OFF_PART_S   110656
#define OFF_S_FINAL  700480
#define OFF_SEG_PART_LL 350752

__global__ __launch_bounds__(256) void votes_kernel(
    const float* __restrict__ x,   // [B, J, 8]
    const float* __restrict__ w,   // [J, 8, 32]
    const float* __restrict__ dc,  // [10, 8]
    int* __restrict__ part_seg,
    int* __restrict__ part_s,
    int* __restrict__ done)
{
    __shared__ int seg_lds[NSEG * SEGSTRIDE];   // 12.4 KB
    __shared__ int s_lds[NSREP * SSTRIDE];      // 16.6 KB

    const int t  = threadIdx.x;
    const int jg = blockIdx.x >> 1;
    const int h  = blockIdx.x & 1;      // batch half
    const int j0 = jg * 8;

    if (blockIdx.x == 0 && t == 0) *done = 0;   // reduce launches after us (stream order)

    for (int i = t; i < NSEG * SEGSTRIDE; i += 256) seg_lds[i] = 0;
    for (int i = t; i < NSREP * SSTRIDE; i += 256) s_lds[i] = 0;

    const int jj   = t >> 5;           // 0..7 : this thread's j
    const int m    = (t >> 3) & 3;     // 0..3 : this thread's vote column
    const int brow = t & 7;            // 0..7 : batch row within iter
    const int j = j0 + jj;

    // ---- W slice (8 i x 8 d for this (j,m)) -> 64 registers, loaded once
    float4 wra[8], wrb[8];
    {
        const float* wp = w + (size_t)j * 256 + m * 8;
        #pragma unroll
        for (int i = 0; i < 8; ++i) {
            wra[i] = *(const float4*)(wp + i * 32);
            wrb[i] = *(const float4*)(wp + i * 32 + 4);
        }
    }
    // ---- all of dc -> 80 registers (global broadcast reads, L2-served)
    float4 dca[10], dcb[10];
    #pragma unroll
    for (int c = 0; c < 10; ++c) {
        dca[c] = *(const float4*)(dc + c * 8);
        dcb[c] = *(const float4*)(dc + c * 8 + 4);
    }

    int* const segp = &seg_lds[((t >> 1) & (NSEG - 1)) * SEGSTRIDE];
    // lanes sharing one b in a wave = {jj&1, m} -> 8 distinct replicas: 1-way
    int* const sp = &s_lds[((t >> 3) & (NSREP - 1)) * SSTRIDE];

    __syncthreads();

    // ---- software-pipelined x loads (1-ahead) to hide HBM latency
    const float* xp0 = x + ((size_t)(h * 64 + brow) * J_POS + j) * 8;
    float4 nx0 = *(const float4*)xp0;
    float4 nx1 = *(const float4*)(xp0 + 4);

    #pragma unroll 1
    for (int it = 0; it < 8; ++it) {
        const int bl = it * 8 + brow;       // local b 0..63
        const float4 x0 = nx0, x1 = nx1;
        if (it < 7) {
            const float* xp = x + ((size_t)(h * 64 + bl + 8) * J_POS + j) * 8;
            nx0 = *(const float4*)xp;
            nx1 = *(const float4*)(xp + 4);
        }
        const float xf[8] = {x0.x,x0.y,x0.z,x0.w,x1.x,x1.y,x1.z,x1.w};

        // ---- one vote: u[8], all operands in registers
        float u[8] = {0,0,0,0,0,0,0,0};
        #pragma unroll
        for (int i = 0; i < 8; ++i) {
            const float xi = xf[i];
            u[0] += xi * wra[i].x; u[1] += xi * wra[i].y;
            u[2] += xi * wra[i].z; u[3] += xi * wra[i].w;
            u[4] += xi * wrb[i].x; u[5] += xi * wrb[i].y;
            u[6] += xi * wrb[i].z; u[7] += xi * wrb[i].w;
        }

        // ---- argmax over 10 caps, dc in registers (strict > = first max, jnp)
        float best = -3.402823466e38f;
        int bc = 0;
        #pragma unroll
        for (int c = 0; c < 10; ++c) {
            const float sim = u[0]*dca[c].x + u[1]*dca[c].y + u[2]*dca[c].z + u[3]*dca[c].w
                            + u[4]*dcb[c].x + u[5]*dcb[c].y + u[6]*dcb[c].z + u[7]*dcb[c].w;
            if (sim > best) { best = sim; bc = c; }
        }

        // ---- fixed-point LDS atomics, fire-and-forget
        const int o = bc * 9;
        const int sb = bl * 8;
        #pragma unroll
        for (int d = 0; d < 8; ++d) {
            const int q = __float2int_rn(u[d] * SEG_SCALE);
            atomicAdd(&segp[o + d], q);
            atomicAdd(&sp[sb + d], q);
        }
        atomicAdd(&segp[o + 8], 1);
    }

    __syncthreads();

    // ---- flush partials: plain coalesced stores, zero global atomics
    if (t < 90) {
        int v = 0;
        #pragma unroll
        for (int r = 0; r < NSEG; ++r) v += seg_lds[r * SEGSTRIDE + t];
        part_seg[blockIdx.x * 96 + t] = v;
    }
    #pragma unroll
    for (int e = t; e < 512; e += 256) {
        int v = 0;
        #pragma unroll
        for (int r = 0; r < NSREP; ++r) v += s_lds[r * SSTRIDE + e];
        part_s[(size_t)blockIdx.x * 512 + e] = v;
    }
}

// 20 blocks: 0..15 s-columns, 16..19 seg-quarters; last-done block runs the final.
__global__ __launch_bounds__(256) void reduce_final_kernel(
    const int* __restrict__ part_seg,
    const int* __restrict__ part_s,
    float* __restrict__ s_final,
    long long* __restrict__ seg_part,
    int* __restrict__ done,
    const float* __restrict__ dc,
    float* __restrict__ out)       // [0,1280): output  [1280,1360): dc_new
{
    __shared__ long long red[64][5];
    __shared__ long long segred[2][96];
    __shared__ float dcn[80];
    __shared__ float sf[1024];
    __shared__ int lastflag;

    const int t = threadIdx.x;
    const int bid = blockIdx.x;

    if (bid < 16) {
        // ---- s column-reduce: 64 cols, 4 chunks of 144 rows (parity h)
        const int g0 = bid * 64;
        const int h = g0 >> 9;
        const int gl = t & 63, chunk = t >> 6;
        const int col = (g0 + gl) & 511;
        long long acc = 0;
        #pragma unroll 8
        for (int i = chunk * 144; i < chunk * 144 + 144; ++i)
            acc += part_s[(size_t)(2 * i + h) * 512 + col];
        red[gl][chunk] = acc;
        __syncthreads();
        if (t < 64) {
            const long long v = red[t][0] + red[t][1] + red[t][2] + red[t][3];
            __hip_atomic_store(&s_final[g0 + t], (float)v * INV_SEG_SCALE,
                               __ATOMIC_RELAXED, __HIP_MEMORY_SCOPE_AGENT);
        }
    } else {
        // ---- seg quarter-reduce: 288 rows, 96 cols, 2 row-chunks
        const int p = bid - 16;
        if (t < 192) {
            const int o = t % 96, rc = t / 96;
            long long acc = 0;
            const int r0 = p * 288 + rc * 144;
            #pragma unroll 8
            for (int i = r0; i < r0 + 144; ++i)
                acc += part_seg[(size_t)i * 96 + o];
            segred[rc][o] = acc;
        }
        __syncthreads();
        if (t < 96)
            __hip_atomic_store(&seg_part[p * 96 + t], segred[0][t] + segred[1][t],
                               __ATOMIC_RELAXED, __HIP_MEMORY_SCOPE_AGENT);
    }

    // ---- completion protocol: release stores, count blocks, last one finalizes
    __threadfence();
    __syncthreads();
    if (t == 0) lastflag = (atomicAdd(done, 1) == 19) ? 1 : 0;
    __syncthreads();
    if (!lastflag) return;
    __threadfence();

    // ---- final (one block): dc_new + output GEMV; agent-scope loads of partials
    #pragma unroll
    for (int r = 0; r < 4; ++r) {
        const int i = r * 256 + t;
        const float v = __hip_atomic_load(&s_final[i], __ATOMIC_RELAXED,
                                          __HIP_MEMORY_SCOPE_AGENT);
        sf[i] = v * (1.0f / NVOTES);
    }
    if (t < 80) {
        const int c = t >> 3, d = t & 7;
        long long sv = 0, cv = 0;
        #pragma unroll
        for (int p = 0; p < 4; ++p) {
            sv += __hip_atomic_load(&seg_part[p * 96 + c * 9 + d], __ATOMIC_RELAXED,
                                    __HIP_MEMORY_SCOPE_AGENT);
            cv += __hip_atomic_load(&seg_part[p * 96 + c * 9 + 8], __ATOMIC_RELAXED,
                                    __HIP_MEMORY_SCOPE_AGENT);
        }
        const float d0 = dc[t];
        const float nd = d0 + ((float)sv * INV_SEG_SCALE - (float)cv * d0) * (1.0f / DENOM);
        dcn[t] = nd;
        out[1280 + t] = nd;
    }
    __syncthreads();

    #pragma unroll
    for (int r = 0; r < 5; ++r) {
        const int idx = r * 256 + t;        // 0..1279
        const int b = idx / 10, c = idx - b * 10;
        float acc = 0.f;
        #pragma unroll
        for (int d = 0; d < 8; ++d) acc += sf[b * 8 + d] * dcn[c * 8 + d];
        out[idx] = acc;
    }
}

extern "C" void kernel_launch(void* const* d_in, const int* in_sizes, int n_in,
                              void* d_out, int out_size, void* d_ws, size_t ws_size,
                              hipStream_t stream) {
    const float* x  = (const float*)d_in[0];
    const float* w  = (const float*)d_in[1];
    const float* dc = (const float*)d_in[2];
    float* out = (float*)d_out;
    int*       done      = (int*)d_ws;
    int*       part_seg  = (int*)d_ws + OFF_PART_SEG;
    int*       part_s    = (int*)d_ws + OFF_PART_S;
    float*     s_final   = (float*)d_ws + OFF_S_FINAL;
    long long* seg_part  = (long long*)d_ws + OFF_SEG_PART_LL;

    votes_kernel<<<1152, 256, 0, stream>>>(x, w, dc, part_seg, part_s, done);
    reduce_final_kernel<<<20, 256, 0, stream>>>(part_seg, part_s, s_final,
                                                seg_part, done, dc, out);
}